// Round 3
// baseline (1064.223 us; speedup 1.0000x reference)
//
#include <hip/hip_runtime.h>
#include <hip/hip_bf16.h>

#define HW 128
#define NPIX 16384          // 128*128
#define CDEP 512

typedef __attribute__((ext_vector_type(8))) short short8;
typedef __attribute__((ext_vector_type(8))) __bf16 bf16x8;
typedef __attribute__((ext_vector_type(4))) float f32x4;
typedef __attribute__((ext_vector_type(4))) unsigned int u32x4;

static __device__ inline bf16x8 asbf(short8 v) {
  union { short8 s; bf16x8 b; } u; u.s = v; return u.b;
}

// round-to-nearest-even f32 -> bf16 bits
static __device__ inline unsigned short f2bf(float x) {
  unsigned u = __float_as_uint(x);
  return (unsigned short)((u + 0x7fffu + ((u >> 16) & 1u)) >> 16);
}
static __device__ inline unsigned pk2(float lo, float hi) {
  return (unsigned)f2bf(lo) | ((unsigned)f2bf(hi) << 16);
}

// ---------------- tar normalize: [16384,512] f32 -> bf16 [p,C] ----------------
__global__ __launch_bounds__(256) void k_norm_tar(const float* __restrict__ ft,
                                                  unsigned short* __restrict__ T) {
  int wave = threadIdx.x >> 6, lane = threadIdx.x & 63;
  int p = blockIdx.x * 4 + wave;
  const float* row = ft + (size_t)p * CDEP + lane * 8;
  float4 v0 = *(const float4*)(row);
  float4 v1 = *(const float4*)(row + 4);
  float s = v0.x*v0.x + v0.y*v0.y + v0.z*v0.z + v0.w*v0.w
          + v1.x*v1.x + v1.y*v1.y + v1.z*v1.z + v1.w*v1.w;
  #pragma unroll
  for (int off = 1; off < 64; off <<= 1) s += __shfl_xor(s, off);
  float sc = 1.0f / fmaxf(sqrtf(s), 1e-12f);
  float vv[8] = {v0.x, v0.y, v0.z, v0.w, v1.x, v1.y, v1.z, v1.w};
  short8 pkv;
  #pragma unroll
  for (int i = 0; i < 8; ++i) pkv[i] = (short)f2bf(vv[i] * sc);
  *(short8*)(T + (size_t)p * CDEP + lane * 8) = pkv;
}

// -------- fused: raw-f32 refs staging (t<->q, loop c) + MFMA + invnorm + softmax --------
// grid 2048 XCD-swizzled; block 256 = 4 waves; WG: 8x8 out px, 16x16 q window.
// LDS layout (verified in R1): byte(q,c') = q*128 + (((c'>>3) ^ (q&7))<<4) + (c'&7)*2
// K in 8 chunks of 64 c, double-buffered 2x32KB.
__global__ __launch_bounds__(256, 2) void k_corr(const unsigned short* __restrict__ Tb,
                                                 const float* __restrict__ fr,
                                                 float* __restrict__ out) {
  __shared__ __align__(16) unsigned char lds[65536];
  const int t = threadIdx.x, lane = t & 63, wave = t >> 6;
  const int lb = blockIdx.x;
  const int logical = (lb & 7) * 256 + (lb >> 3);   // bijective: XCD <-> batch
  const int bx = logical & 15, by = (logical >> 4) & 15, bz = logical >> 8;
  const int wy = wave >> 1, wx = wave & 1;
  const int mA = lane & 15, kg = lane >> 4;

  // ---- staging: thread t <-> window pixel q = t ----
  const int gy = by * 8 - 4 + (t >> 4), gx = bx * 8 - 4 + (t & 15);
  const bool valid = ((unsigned)gy < 128u) && ((unsigned)gx < 128u);
  const int gp = valid ? (gy * HW + gx) : 0;
  const float* frb = fr + (size_t)bz * CDEP * NPIX;
  const int wrow = t * 128, wkey = (t & 7) << 4;

  // ---- B-read offsets (R1-verified): step1 = qoff ^ 64 ----
  int qoff[9];
  #pragma unroll
  for (int tt = 0; tt < 9; ++tt) {
    int idx = tt * 16 + mA;
    int q = (wy * 4 + idx / 12) * 16 + (wx * 4 + idx % 12);
    qoff[tt] = q * 128 + (((kg << 4)) ^ ((q & 7) << 4));
  }

  const int py = by * 8 + wy * 4 + (mA >> 2), px = bx * 8 + wx * 4 + (mA & 3);
  const short* arow = (const short*)Tb + (size_t)(py * HW + px) * CDEP + kg * 8;

  f32x4 acc[9];
  #pragma unroll
  for (int tt = 0; tt < 9; ++tt) acc[tt] = (f32x4){0.f, 0.f, 0.f, 0.f};
  float ssq = 0.f;
  float v[64];

#define LOADCH(C0) { \
  _Pragma("unroll") \
  for (int j = 0; j < 64; ++j) { \
    v[j] = 0.0f; \
    if (valid) v[j] = frb[(size_t)((C0) + j) * NPIX + gp]; \
  } }

#define WRITECH(BUFO) { \
  _Pragma("unroll") \
  for (int s = 0; s < 8; ++s) { \
    u32x4 d; \
    _Pragma("unroll") \
    for (int w = 0; w < 4; ++w) { \
      float lo = v[s*8 + 2*w], hi = v[s*8 + 2*w + 1]; \
      ssq += lo*lo + hi*hi; \
      d[w] = pk2(lo, hi); \
    } \
    *(u32x4*)(lds + (BUFO) + wrow + ((s << 4) ^ wkey)) = d; \
  } }

  // ---- prologue: chunk 0 -> buf0 ----
  LOADCH(0);
  WRITECH(0);
  short8 a0c = *(const short8*)(arow);
  short8 a1c = *(const short8*)(arow + 32);
  __syncthreads();

  // ---- main loop: 8 chunks of 64 c ----
  #pragma unroll
  for (int ch = 0; ch < 8; ++ch) {
    short8 a0n, a1n;
    if (ch < 7) {                          // T14: issue next-chunk loads early
      LOADCH((ch + 1) * 64);
      a0n = *(const short8*)(arow + (ch + 1) * 64);
      a1n = *(const short8*)(arow + (ch + 1) * 64 + 32);
    }
    const int bufo = (ch & 1) << 15;
    __builtin_amdgcn_s_setprio(1);
    #pragma unroll
    for (int step = 0; step < 2; ++step) {
      bf16x8 af = asbf(step ? a1c : a0c);
      const int sx = step << 6;
      #pragma unroll
      for (int tt = 0; tt < 9; ++tt) {
        short8 bv = *(const short8*)(lds + bufo + (qoff[tt] ^ sx));
        acc[tt] = __builtin_amdgcn_mfma_f32_16x16x32_bf16(af, asbf(bv), acc[tt], 0, 0, 0);
      }
    }
    __builtin_amdgcn_s_setprio(0);
    if (ch < 7) {                          // write next chunk into other buffer
      const int nbufo = ((ch + 1) & 1) << 15;
      WRITECH(nbufo);
      a0c = a0n; a1c = a1n;
    }
    __syncthreads();
  }

  // ---- epilogue: per-q inverse norm (thread-local!) + S spill + softmax ----
  float* inv_lds = (float*)(lds + 37888);          // [256] floats
  inv_lds[t] = 1.0f / fmaxf(sqrtf(ssq), 1e-12f);   // q = t

  const int SSTR = 148;
  float* S = (float*)lds + wave * 16 * SSTR;       // 4 waves x 16 x 148 = 37888 B
  #pragma unroll
  for (int tt = 0; tt < 9; ++tt) {
    #pragma unroll
    for (int r = 0; r < 4; ++r)
      S[(kg * 4 + r) * SSTR + tt * 16 + mA] = acc[tt][r];
  }
  __syncthreads();

  // softmax: 4 lanes per pixel over 81 window values
  const int mrow = lane >> 2, s4 = lane & 3;
  const int myy = mrow >> 2, mxx = mrow & 3;
  const float* Srow = S + mrow * SSTR;
  float vals[21];
  float mx = -3.0e38f;
  #pragma unroll
  for (int i = 0; i < 21; ++i) {
    int j = s4 + 4 * i;
    if (j < 81) {
      int dy = j / 9, dx = j % 9;
      int qw = (wy * 4 + myy + dy) * 16 + wx * 4 + mxx + dx;
      float val = Srow[(myy + dy) * 12 + (mxx + dx)] * inv_lds[qw];
      vals[i] = val;
      mx = fmaxf(mx, val);
    }
  }
  mx = fmaxf(mx, __shfl_xor(mx, 1));
  mx = fmaxf(mx, __shfl_xor(mx, 2));
  float sum = 0.f;
  #pragma unroll
  for (int i = 0; i < 21; ++i) {
    int j = s4 + 4 * i;
    if (j < 81) { float e = __expf(vals[i] - mx); vals[i] = e; sum += e; }
  }
  sum += __shfl_xor(sum, 1);
  sum += __shfl_xor(sum, 2);
  float rs = 1.0f / sum;
  const int pg = (by * 8 + wy * 4 + myy) * HW + (bx * 8 + wx * 4 + mxx);
  float* op = out + ((size_t)bz * NPIX + pg) * 81;
  #pragma unroll
  for (int i = 0; i < 21; ++i) {
    int j = s4 + 4 * i;
    if (j < 81) op[j] = vals[i] * rs;
  }
#undef LOADCH
#undef WRITECH
}

extern "C" void kernel_launch(void* const* d_in, const int* in_sizes, int n_in,
                              void* d_out, int out_size, void* d_ws, size_t ws_size,
                              hipStream_t stream) {
  const float* ft = (const float*)d_in[0];
  const float* fr = (const float*)d_in[1];
  float* out = (float*)d_out;
  unsigned short* T = (unsigned short*)d_ws;   // 16 MB bf16 normalized tar

  k_norm_tar<<<dim3(NPIX / 4), dim3(256), 0, stream>>>(ft, T);
  k_corr<<<dim3(2048), dim3(256), 0, stream>>>(T, fr, out);
}

// Round 4
// 165.942 us; speedup vs baseline: 6.4132x; 6.4132x over previous
//
#include <hip/hip_runtime.h>
#include <hip/hip_bf16.h>

#define HW 128
#define NPIX 16384          // 128*128
#define CDEP 512
#define NB 8

typedef __attribute__((ext_vector_type(8))) short short8;
typedef __attribute__((ext_vector_type(8))) __bf16 bf16x8;
typedef __attribute__((ext_vector_type(4))) float f32x4;

static __device__ inline bf16x8 asbf(short8 v) {
  union { short8 s; bf16x8 b; } u; u.s = v; return u.b;
}
// round-to-nearest-even f32 -> bf16 bits
static __device__ inline unsigned short f2bf(float x) {
  unsigned u = __float_as_uint(x);
  return (unsigned short)((u + 0x7fffu + ((u >> 16) & 1u)) >> 16);
}
static __device__ inline unsigned pk2(float lo, float hi) {
  return (unsigned)f2bf(lo) | ((unsigned)f2bf(hi) << 16);
}
// async global->LDS, 16B per lane, linear LDS dest (wave-uniform base + lane*16)
static __device__ inline void gload16(const void* g, void* l) {
  __builtin_amdgcn_global_load_lds(
      (const __attribute__((address_space(1))) unsigned int*)g,
      (__attribute__((address_space(3))) unsigned int*)l, 16, 0, 0);
}

// ---------------- tar normalize: [16384,512] f32 -> bf16 [p,C]; also zero the zero-page ----
__global__ __launch_bounds__(256) void k_norm_tar(const float* __restrict__ ft,
                                                  unsigned short* __restrict__ T,
                                                  float* __restrict__ zp) {
  if (blockIdx.x == 0 && threadIdx.x < 64)
    ((f32x4*)zp)[threadIdx.x] = (f32x4){0.f, 0.f, 0.f, 0.f};
  int wave = threadIdx.x >> 6, lane = threadIdx.x & 63;
  int p = blockIdx.x * 4 + wave;
  const float* row = ft + (size_t)p * CDEP + lane * 8;
  float4 v0 = *(const float4*)(row);
  float4 v1 = *(const float4*)(row + 4);
  float s = v0.x*v0.x + v0.y*v0.y + v0.z*v0.z + v0.w*v0.w
          + v1.x*v1.x + v1.y*v1.y + v1.z*v1.z + v1.w*v1.w;
  #pragma unroll
  for (int off = 1; off < 64; off <<= 1) s += __shfl_xor(s, off);
  float sc = 1.0f / fmaxf(sqrtf(s), 1e-12f);
  float vv[8] = {v0.x, v0.y, v0.z, v0.w, v1.x, v1.y, v1.z, v1.w};
  short8 pkv;
  #pragma unroll
  for (int i = 0; i < 8; ++i) pkv[i] = (short)f2bf(vv[i] * sc);
  *(short8*)(T + (size_t)p * CDEP + lane * 8) = pkv;
}

// -------- refs normalize + transpose: [b,C,p] f32 -> PRE-SWIZZLED bf16 rows --------
// Row p (1 KB): byte(c) = (c>>6)*128 + (((c&63)>>3 ^ key)<<4) + (c&7)*2, key=(p+4)&7.
__global__ __launch_bounds__(256) void k_norm_refs(const float* __restrict__ fr,
                                                   unsigned short* __restrict__ R,
                                                   int b_offset) {
  __shared__ float lds[32][CDEP + 1];
  __shared__ float psum[32][8];
  __shared__ float inv[32];
  int b = b_offset + blockIdx.z;
  int q0 = blockIdx.x * 32;
  const float* src = fr + (size_t)b * CDEP * NPIX;
  int t = threadIdx.x;

  // phase A: coalesced float4 loads along p, transpose into LDS [p][c]
  int g = t & 7, cy = t >> 3;
  #pragma unroll
  for (int it = 0; it < 16; ++it) {
    int c = it * 32 + cy;
    float4 v = *(const float4*)(src + (size_t)c * NPIX + q0 + g * 4);
    lds[g*4 + 0][c] = v.x;
    lds[g*4 + 1][c] = v.y;
    lds[g*4 + 2][c] = v.z;
    lds[g*4 + 3][c] = v.w;
  }
  __syncthreads();

  // phase B: per-pixel sum of squares
  int p = t & 31, part = t >> 5;
  float s = 0.f;
  #pragma unroll
  for (int j = 0; j < 64; ++j) { float v = lds[p][part*64 + j]; s += v * v; }
  psum[p][part] = s;
  __syncthreads();
  if (t < 32) {
    float a = 0.f;
    #pragma unroll
    for (int j = 0; j < 8; ++j) a += psum[t][j];
    inv[t] = 1.0f / fmaxf(sqrtf(a), 1e-12f);
  }
  __syncthreads();

  // phase C: scale, convert, swizzled coalesced stores
  unsigned char* dstb = (unsigned char*)(R + (size_t)blockIdx.z * NPIX * CDEP);
  const int chunk = t >> 5, sl = (t & 31) >> 2, w4 = (t & 3) * 4;
  #pragma unroll 4
  for (int j = 0; j < 32; ++j) {
    int pg = q0 + j;
    int key = (pg + 4) & 7;
    int off = chunk * 128 + ((sl ^ key) << 4) + w4;
    float sc = inv[j];
    *(unsigned*)(dstb + (size_t)pg * 1024 + off) = pk2(lds[j][2*t] * sc, lds[j][2*t + 1] * sc);
  }
}

// -------- corr GEMM + softmax; staging via global_load_lds from pre-swizzled R --------
// grid: nwg (XCD-swizzled, per-XCD chunk = 1<<shift); block 256 = 4 waves.
// WG: 8x8 out px, 16x16 q window, K=512 in 8 chunks of 64.
__global__ __launch_bounds__(256, 2) void k_corr(const unsigned short* __restrict__ Tb,
                                                 const unsigned short* __restrict__ R,
                                                 const float* __restrict__ zp,
                                                 float* __restrict__ out,
                                                 int b_offset, int shift) {
  __shared__ __align__(16) unsigned char lds[65536];   // 2 x 32KB staging; epilogue reuses
  const int t = threadIdx.x, lane = t & 63, wave = t >> 6;
  const int lb = blockIdx.x;
  const int logical = (lb & 7) * (1 << shift) + (lb >> 3);  // bijective XCD swizzle
  const int bx = logical & 15, by = (logical >> 4) & 15, bz = logical >> 8;
  const int wy = wave >> 1, wx = wave & 1;
  const int mA = lane & 15, kg = lane >> 4;
  const unsigned char* Rb = (const unsigned char*)(R + (size_t)bz * NPIX * CDEP);

  // ---- staging row pointers: round r covers q = r*32 + wave*8 + (lane>>3) ----
  const unsigned char* ptr8[8];
  #pragma unroll
  for (int r = 0; r < 8; ++r) {
    int q = r * 32 + wave * 8 + (lane >> 3);
    int gy = by * 8 - 4 + (q >> 4), gx = bx * 8 - 4 + (q & 15);
    bool valid = ((unsigned)gy < 128u) && ((unsigned)gx < 128u);
    const unsigned char* base = valid ? (Rb + (size_t)(gy * HW + gx) * 1024)
                                      : (const unsigned char*)zp;
    ptr8[r] = base + (lane & 7) * 16;
  }

  // ---- B-read offsets (R1-verified): byte = q*128 + ((kg ^ (q&7))<<4), step flips bit6 ----
  int qoff[9];
  #pragma unroll
  for (int tt = 0; tt < 9; ++tt) {
    int idx = tt * 16 + mA;
    int q = (wy * 4 + idx / 12) * 16 + (wx * 4 + idx % 12);
    qoff[tt] = q * 128 + ((kg << 4) ^ ((q & 7) << 4));
  }

  // ---- A fragments fully in registers ----
  const int py = by * 8 + wy * 4 + (mA >> 2), px = bx * 8 + wx * 4 + (mA & 3);
  const short* arow = (const short*)Tb + (size_t)(py * HW + px) * CDEP + kg * 8;
  short8 a[16];
  #pragma unroll
  for (int kk = 0; kk < 16; ++kk) a[kk] = *(const short8*)(arow + kk * 32);

  f32x4 acc[9];
  #pragma unroll
  for (int tt = 0; tt < 9; ++tt) acc[tt] = (f32x4){0.f, 0.f, 0.f, 0.f};

  // ---- prologue: stage chunk 0 into buf0 ----
  #pragma unroll
  for (int r = 0; r < 8; ++r)
    gload16(ptr8[r], lds + r * 4096 + wave * 1024);
  __syncthreads();

  // ---- main loop: 8 chunks of 64 c, double-buffered ----
  #pragma unroll
  for (int ch = 0; ch < 8; ++ch) {
    if (ch < 7) {
      const int nb = ((ch + 1) & 1) << 15;
      #pragma unroll
      for (int r = 0; r < 8; ++r)
        gload16(ptr8[r] + (ch + 1) * 128, lds + nb + r * 4096 + wave * 1024);
    }
    const int bufo = (ch & 1) << 15;
    __builtin_amdgcn_s_setprio(1);
    #pragma unroll
    for (int step = 0; step < 2; ++step) {
      bf16x8 af = asbf(a[ch * 2 + step]);
      const int sx = step << 6;
      #pragma unroll
      for (int tt = 0; tt < 9; ++tt) {
        short8 bv = *(const short8*)(lds + bufo + (qoff[tt] ^ sx));
        acc[tt] = __builtin_amdgcn_mfma_f32_16x16x32_bf16(af, asbf(bv), acc[tt], 0, 0, 0);
      }
    }
    __builtin_amdgcn_s_setprio(0);
    __syncthreads();   // drains this wave's gload_lds (vmcnt 0) + barrier
  }

  // ---- epilogue: S spill (C/D: col=lane&15, row=kg*4+reg) + softmax ----
  const int SSTR = 148;
  float* S = (float*)lds + wave * 16 * SSTR;    // 4 x 16 x 148 x 4B = 37888 B
  #pragma unroll
  for (int tt = 0; tt < 9; ++tt) {
    #pragma unroll
    for (int r = 0; r < 4; ++r)
      S[(kg * 4 + r) * SSTR + tt * 16 + mA] = acc[tt][r];
  }
  __syncthreads();

  // softmax: 4 lanes per pixel over 81 window values
  const int mrow = lane >> 2, s4 = lane & 3;
  const int myy = mrow >> 2, mxx = mrow & 3;
  const float* Srow = S + mrow * SSTR;
  float vals[21];
  float mx = -3.0e38f;
  #pragma unroll
  for (int i = 0; i < 21; ++i) {
    int j = s4 + 4 * i;
    if (j < 81) {
      int dy = j / 9, dx = j % 9;
      float v = Srow[(myy + dy) * 12 + (mxx + dx)];
      vals[i] = v;
      mx = fmaxf(mx, v);
    }
  }
  mx = fmaxf(mx, __shfl_xor(mx, 1));
  mx = fmaxf(mx, __shfl_xor(mx, 2));
  float sum = 0.f;
  #pragma unroll
  for (int i = 0; i < 21; ++i) {
    int j = s4 + 4 * i;
    if (j < 81) { float e = __expf(vals[i] - mx); vals[i] = e; sum += e; }
  }
  sum += __shfl_xor(sum, 1);
  sum += __shfl_xor(sum, 2);
  float rs = 1.0f / sum;
  const int pg = (by * 8 + wy * 4 + myy) * HW + (bx * 8 + wx * 4 + mxx);
  float* op = out + ((size_t)(b_offset + bz) * NPIX + pg) * 81;
  #pragma unroll
  for (int i = 0; i < 21; ++i) {
    int j = s4 + 4 * i;
    if (j < 81) op[j] = vals[i] * rs;
  }
}

extern "C" void kernel_launch(void* const* d_in, const int* in_sizes, int n_in,
                              void* d_out, int out_size, void* d_ws, size_t ws_size,
                              hipStream_t stream) {
  const float* ft = (const float*)d_in[0];
  const float* fr = (const float*)d_in[1];
  float* out = (float*)d_out;

  const size_t T_BYTES = (size_t)NPIX * CDEP * 2;            // 16 MB
  const size_t ZP_OFF  = T_BYTES;                            // 1 KB zero page
  const size_t R_OFF   = T_BYTES + 4096;
  const size_t R_FULL  = (size_t)NB * NPIX * CDEP * 2;       // 128 MB

  unsigned short* T = (unsigned short*)d_ws;
  float* zp = (float*)((char*)d_ws + ZP_OFF);
  unsigned short* R = (unsigned short*)((char*)d_ws + R_OFF);

  k_norm_tar<<<dim3(NPIX / 4), dim3(256), 0, stream>>>(ft, T, zp);
  if (ws_size >= R_OFF + R_FULL) {
    k_norm_refs<<<dim3(512, 1, NB), dim3(256), 0, stream>>>(fr, R, 0);
    k_corr<<<dim3(2048), dim3(256), 0, stream>>>(T, R, zp, out, 0, 8);
  } else {
    for (int bb = 0; bb < NB; ++bb) {
      k_norm_refs<<<dim3(512, 1, 1), dim3(256), 0, stream>>>(fr, R, bb);
      k_corr<<<dim3(256), dim3(256), 0, stream>>>(T, R, zp, out, bb, 5);
    }
  }
}